// Round 18
// baseline (178.663 us; speedup 1.0000x reference)
//
#include <hip/hip_runtime.h>
#include <hip/hip_bf16.h>

// Talking-heads attention + GFSA reaction, MI355X (gfx950).
//   attn_final = (1-2λ)A + 3λ A²  applied to v:
//   ctx = (1-2λ)(A@v) + 3λ A@(A@v)   -- never forms A@A.
// R17->R18: BK as template param; BK=128 for the 64x64-tile skinny GEMMs
// (G3/G4/G5) -> K-iterations 16->8 (G5 12->6), halving the per-block
// serial stage->drain->barrier chain. LDS 32KB at 64x64/BK=128 (no
// occupancy cliff; m132's regression was the 128x128 shape). BK=128 laid
// out as two 64-wide sub-tiles, each with the verified XOR swizzle.

typedef __bf16 bf16x8 __attribute__((ext_vector_type(8)));
typedef float f32x4 __attribute__((ext_vector_type(4)));
typedef _Float16 half4v __attribute__((ext_vector_type(4)));
typedef _Float16 half2v __attribute__((ext_vector_type(2)));
typedef __fp16 fp16x2 __attribute__((ext_vector_type(2)));

#define DI __device__ __forceinline__

DI unsigned short f2bf(float f) {
  union { float f; unsigned u; } x; x.f = f;
  unsigned r = x.u + 0x7FFF + ((x.u >> 16) & 1);   // RNE
  return (unsigned short)(r >> 16);
}
DI float bf2f(unsigned short u) {
  union { unsigned u; float f; } x; x.u = ((unsigned)u) << 16; return x.f;
}
DI unsigned short f2h(float f) {
  union { _Float16 h; unsigned short u; } x;
  x.h = (_Float16)f;
  return x.u;
}
DI unsigned pk_bf16(float a, float b) {   // packs (a,b) -> 2xbf16, RNE
  unsigned r;
  asm("v_cvt_pk_bf16_f32 %0, %1, %2" : "=v"(r) : "v"(a), "v"(b));
  return r;
}
DI half2v pkrtz(float a, float b) {       // f32 pair -> packed f16 (RTZ)
  fp16x2 t = __builtin_amdgcn_cvt_pkrtz(a, b);
  union { fp16x2 a; half2v b; } u;
  u.a = t;
  return u.b;
}
DI void gload16(const unsigned short* g, unsigned short* l) {
  __builtin_amdgcn_global_load_lds(
      (const __attribute__((address_space(1))) unsigned int*)g,
      (__attribute__((address_space(3))) unsigned int*)l, 16, 0, 0);
}

DI f32x4 mfma1616(half4v a, half4v b, f32x4 c) {
  return __builtin_amdgcn_mfma_f32_16x16x16f16(a, b, c, 0, 0, 0);
}

struct GP {
  const unsigned short* A;
  const unsigned short* B;
  int K, lda, ldb, ldc;
  long sA, sB, sC;
  unsigned short* C;
  const unsigned short* C2;
  float* outF;
  const float* bias;
  const float* lamb;
  unsigned short* q_out;
  unsigned short* k_out;
  unsigned short* vT_out;
};

// C = A @ B^T, A:[M,K] bf16 row-major(lda), B:[N,K] bf16 row-major(ldb).
// Wave grid WMxWN, per-wave FMxFN frags of mfma_f32_16x16x32_bf16.
// BM=WM*FM*16, BN=WN*FN*16. K-step = BK (64 or 128); BK=128 stored as two
// 64-wide sub-tiles, each XOR-swizzled (chunk ^ (row&7)) via pre-swizzled
// global source + linear global_load_lds (16B). STC: 1=bf16 staged C, 2=f16.
// SWZ: XCD-aware bijective block remap (requires gridDim.x*gridDim.y % 8 == 0).
template<int WM, int WN, int FM, int FN, int EPI, int STC, int SWZ, int BK>
__global__ __launch_bounds__(256) void gemm_bt(GP p) {
  constexpr int BM = WM * FM * 16, BN = WN * FN * 16;
  constexpr int CPRK = BK / 8;            // 8-elem chunks per row
  constexpr int LTILES = BM * BK + BN * BK;
  constexpr int LSZ = LTILES > (BM * BN) ? LTILES : (BM * BN);
  __shared__ __align__(16) unsigned short ls[LSZ];
  unsigned short* lA = ls;
  unsigned short* lB = ls + BM * BK;
  const int tid = threadIdx.x, lane = tid & 63, wid = tid >> 6;
  const int wr = wid / WN, wc = wid % WN;
  int bx = blockIdx.x, by = blockIdx.y;
  if constexpr (SWZ) {
    int gx = gridDim.x;
    int nwg = gx * gridDim.y;
    int flat = by * gx + bx;
    int swz = (flat & 7) * (nwg >> 3) + (flat >> 3);
    bx = swz % gx;
    by = swz / gx;
  }
  const int m0 = by * BM, n0 = bx * BN;
  const int bz = blockIdx.z;
  const unsigned short* Ab = p.A + (long)bz * p.sA;
  const unsigned short* Bb = p.B + (long)bz * p.sB;

  f32x4 acc[FM][FN];
#pragma unroll
  for (int i = 0; i < FM; ++i)
#pragma unroll
    for (int j = 0; j < FN; ++j) acc[i][j] = (f32x4)0.f;

  for (int k0 = 0; k0 < p.K; k0 += BK) {
    __syncthreads();
#pragma unroll
    for (int i = 0; i < BM * BK / 2048; ++i) {
      int c = tid + i * 256, r = c / CPRK, cc = c % CPRK;
      int sub = cc >> 3, kc = cc & 7, kg = kc ^ (r & 7);
      gload16(Ab + (long)(m0 + r) * p.lda + k0 + sub * 64 + kg * 8,
              &lA[c * 8]);
    }
#pragma unroll
    for (int i = 0; i < BN * BK / 2048; ++i) {
      int c = tid + i * 256, r = c / CPRK, cc = c % CPRK;
      int sub = cc >> 3, kc = cc & 7, kg = kc ^ (r & 7);
      gload16(Bb + (long)(n0 + r) * p.ldb + k0 + sub * 64 + kg * 8,
              &lB[c * 8]);
    }
    __syncthreads();
#pragma unroll
    for (int half = 0; half < BK / 32; ++half) {
      bf16x8 af[FM], bfr[FN];
#pragma unroll
      for (int mi = 0; mi < FM; ++mi) {
        int r = wr * FM * 16 + mi * 16 + (lane & 15);
        int kcf = half * 4 + (lane >> 4);
        int sub = kcf >> 3, kcl = kcf & 7;
        af[mi] = *(const bf16x8*)&lA[r * BK + sub * 64 + ((kcl ^ (r & 7)) << 3)];
      }
#pragma unroll
      for (int ni = 0; ni < FN; ++ni) {
        int r = wc * FN * 16 + ni * 16 + (lane & 15);
        int kcf = half * 4 + (lane >> 4);
        int sub = kcf >> 3, kcl = kcf & 7;
        bfr[ni] = *(const bf16x8*)&lB[r * BK + sub * 64 + ((kcl ^ (r & 7)) << 3)];
      }
#pragma unroll
      for (int mi = 0; mi < FM; ++mi)
#pragma unroll
        for (int ni = 0; ni < FN; ++ni)
          acc[mi][ni] = __builtin_amdgcn_mfma_f32_16x16x32_bf16(
              af[mi], bfr[ni], acc[mi][ni], 0, 0, 0);
    }
  }

  if constexpr (STC >= 1) {
    // Stage C-tile in LDS (chunk-XOR swizzle), then coalesced 16B writes.
    __syncthreads();
#pragma unroll
    for (int mi = 0; mi < FM; ++mi)
#pragma unroll
      for (int ni = 0; ni < FN; ++ni) {
        int row = wr * FM * 16 + mi * 16 + (lane >> 4) * 4;
        int col = wc * FN * 16 + ni * 16 + (lane & 15);
#pragma unroll
        for (int r2 = 0; r2 < 4; ++r2) {
          float v = acc[mi][ni][r2];
          ls[(row + r2) * BN + (col ^ ((row + r2) & 7) * 8)] =
              (STC == 2) ? f2h(v) : f2bf(v);
        }
      }
    __syncthreads();
    constexpr int CPR = BN / 8;           // 16B chunks per row
#pragma unroll
    for (int idx = tid; idx < BM * CPR; idx += 256) {
      int row = idx / CPR, cc = idx % CPR;
      uint4 d = *(const uint4*)&ls[row * BN + (cc ^ (row & 7)) * 8];
      *(uint4*)&p.C[(long)bz * p.sC + (long)(m0 + row) * p.ldc + n0 + cc * 8] = d;
    }
    return;
  }

#pragma unroll
  for (int mi = 0; mi < FM; ++mi)
#pragma unroll
    for (int ni = 0; ni < FN; ++ni) {
      const int rowb = m0 + wr * FM * 16 + mi * 16 + (lane >> 4) * 4;
      const int col = n0 + wc * FN * 16 + ni * 16 + (lane & 15);
      if constexpr (EPI == 1) {            // qkv scatter: q*SCALE, k, v^T
        int s = col / 768, rem = col - s * 768;
        int h = rem >> 6, d = rem & 63;
        int b = rowb >> 10, n = rowb & 1023;
        long ho = (long)(b * 12 + h);
        if (s == 2) {                      // 4 consecutive n -> one 8B store
          uint2 pk = { pk_bf16(acc[mi][ni][0], acc[mi][ni][1]),
                       pk_bf16(acc[mi][ni][2], acc[mi][ni][3]) };
          *(uint2*)&p.vT_out[(ho * 64 + d) * 1024 + n] = pk;
        } else {
#pragma unroll
          for (int r2 = 0; r2 < 4; ++r2) {
            float v = acc[mi][ni][r2];
            if (s == 0)
              p.q_out[(ho * 1024 + n + r2) * 64 + d] = f2bf(v * 0.125f);
            else
              p.k_out[(ho * 1024 + n + r2) * 64 + d] = f2bf(v);
          }
        }
      } else if constexpr (EPI == 2) {     // fp32 out + bias
        float bb = p.bias[col];
#pragma unroll
        for (int r2 = 0; r2 < 4; ++r2)
          p.outF[(long)(rowb + r2) * p.ldc + col] = acc[mi][ni][r2] + bb;
      } else if constexpr (EPI == 4) {     // ctx = (1-2λ)U + 3λ·Y
        int b = bz / 12, h = bz - b * 12;
        float lam = p.lamb[h];
        float a1 = 1.f - 2.f * lam, c3 = 3.f * lam;
        uint2 uq = *(const uint2*)&p.C2[(long)bz * 65536 + (long)col * 1024 + rowb];
        float uv[4] = { bf2f((unsigned short)(uq.x & 0xffff)),
                        bf2f((unsigned short)(uq.x >> 16)),
                        bf2f((unsigned short)(uq.y & 0xffff)),
                        bf2f((unsigned short)(uq.y >> 16)) };
#pragma unroll
        for (int r2 = 0; r2 < 4; ++r2) {
          float val = a1 * uv[r2] + c3 * acc[mi][ni][r2];
          p.C[((long)(b * 1024 + rowb + r2)) * 768 + h * 64 + col] = f2bf(val);
        }
      }
    }
}

// One block per (b,n) row. MFMA-based mix, WAVE-LOCAL phases (R12):
//   wave w owns columns [w*256, (w+1)*256): stages its slab (12 rows x 32
//   16B chunks via per-lane uint4 loads -> max MLP), premixes it
//   (L = W1f @ Sfrag + b1 via 16x16x16f16, k>=12 rows clamped under zero
//   weights), exp in regs, postmixes (swapped: out^T = P^T @ W2^T) into its
//   slab, stores its slab. Intra-wave LDS ordering replaces barriers; ONLY
//   the softmax-sum exchange barrier remains.
__global__ __launch_bounds__(256) void mix_softmax(
    unsigned short* S, const float* W1, const float* b1,
    const float* W2, const float* b2) {
  constexpr int RS = 1032;
  __shared__ __align__(16) unsigned short sld[12 * RS];
  __shared__ float red[4][16];
  const int tid = threadIdx.x, lane = tid & 63, wid = tid >> 6;
  const int bn = blockIdx.x, b = bn >> 10, n = bn & 1023;
  unsigned short* Sb = S + ((long)(b * 12) * 1024 + n) * 1024;

  // wave-local staging: 12 rows x 32 chunks of this wave's 256-col slab
#pragma unroll
  for (int i = 0; i < 6; ++i) {
    int flat = i * 64 + lane;                 // 0..383
    int row = flat >> 5, ch = (flat & 31) + wid * 32;
    uint4 d = *(const uint4*)(Sb + (long)row * 1048576 + ch * 8);
    *(uint4*)&sld[row * RS + ch * 8] = d;
  }
  // W fragments (A operand: row=lane&15 -> g, k=(lane>>4)*4+j -> h) + biases
  const int gr = lane & 15, kb = (lane >> 4) * 4;
  half4v w1f, w2f;
  f32x4 bias1;
  int ro[4];
#pragma unroll
  for (int j = 0; j < 4; ++j) {
    int k = kb + j;
    bool vw = (gr < 12) && (k < 12);
    w1f[j] = vw ? (_Float16)W1[gr * 12 + k] : (_Float16)0.f;
    w2f[j] = vw ? (_Float16)W2[gr * 12 + k] : (_Float16)0.f;
    bias1[j] = (k < 12) ? b1[k] : 0.f;       // premix D row = kb + r
    ro[j] = (k < 12 ? k : 11) * RS;          // clamped B-frag row offset
  }
  const float b2v = (gr < 12) ? b2[gr] : 0.f;  // postmix D col = gr
  f32x4 bias2v = { b2v, b2v, b2v, b2v };

  // premix on own slab (no barrier: intra-wave LDS ordering suffices)
  const _Float16* sh = (const _Float16*)sld;
  const int colb = wid * 256 + (lane & 15);
  f32x4 pv[16];
  float ssum[4] = { 0.f, 0.f, 0.f, 0.f };
#pragma unroll
  for (int c = 0; c < 16; ++c) {
    int col = colb + c * 16;
    half4v bf;
#pragma unroll
    for (int j = 0; j < 4; ++j) bf[j] = sh[ro[j] + col];
    f32x4 acc = mfma1616(w1f, bf, bias1);
#pragma unroll
    for (int r = 0; r < 4; ++r) {
      float e = __expf(acc[r]);
      pv[c][r] = e;
      ssum[r] += e;
    }
  }
#pragma unroll
  for (int r = 0; r < 4; ++r) {
#pragma unroll
    for (int m = 1; m < 16; m <<= 1) ssum[r] += __shfl_xor(ssum[r], m);
  }
  if ((lane & 15) == 0) {
#pragma unroll
    for (int r = 0; r < 4; ++r) red[wid][kb + r] = ssum[r];
  }
  __syncthreads();                           // the ONE cross-wave exchange
  float rinv[4];
#pragma unroll
  for (int r = 0; r < 4; ++r)
    rinv[r] = 1.f / (red[0][kb + r] + red[1][kb + r] +
                     red[2][kb + r] + red[3][kb + r]);
  // postmix into own slab, swapped: D[m-local][g]
#pragma unroll
  for (int c = 0; c < 16; ++c) {
    union { half4v h4; half2v h2[2]; } pf;
    pf.h2[0] = pkrtz(pv[c][0] * rinv[0], pv[c][1] * rinv[1]);
    pf.h2[1] = pkrtz(pv[c][2] * rinv[2], pv[c][3] * rinv[3]);
    f32x4 o = mfma1616(pf.h4, w2f, bias2v);
    if (gr < 12) {
      uint2 ov = { pk_bf16(o[0], o[1]), pk_bf16(o[2], o[3]) };
      *(uint2*)&sld[gr * RS + wid * 256 + c * 16 + kb] = ov;
    }
  }
  // store own slab (no barrier: all slab writes were by this wave)
#pragma unroll
  for (int i = 0; i < 6; ++i) {
    int flat = i * 64 + lane;
    int row = flat >> 5, ch = (flat & 31) + wid * 32;
    *(uint4*)(Sb + (long)row * 1048576 + ch * 8) =
        *(const uint4*)&sld[row * RS + ch * 8];
  }
}

// One kernel converting three fp32->bf16 regions (fewer graph nodes).
__global__ __launch_bounds__(256) void cvt3(
    const float* a, const float* b, const float* c,
    unsigned short* oa, unsigned short* ob, unsigned short* oc,
    int na, int nb, int nc) {
  int i = blockIdx.x * 256 + threadIdx.x;
  const float* src;
  unsigned short* dst;
  int j = i;
  if (i < na) { src = a; dst = oa; }
  else if (i < na + nb) { src = b; dst = ob; j = i - na; }
  else if (i < na + nb + nc) { src = c; dst = oc; j = i - na - nb; }
  else return;
  float4 v = *(const float4*)(src + (long)j * 4);
  uint2 o = { pk_bf16(v.x, v.y), pk_bf16(v.z, v.w) };
  *(uint2*)(dst + (long)j * 4) = o;
}

extern "C" void kernel_launch(void* const* d_in, const int* in_sizes, int n_in,
                              void* d_out, int out_size, void* d_ws,
                              size_t ws_size, hipStream_t stream) {
  const float* x     = (const float*)d_in[0];
  const float* qkv_w = (const float*)d_in[1];
  const float* W1    = (const float*)d_in[2];
  const float* b1    = (const float*)d_in[3];
  const float* W2    = (const float*)d_in[4];
  const float* b2    = (const float*)d_in[5];
  const float* lamb  = (const float*)d_in[6];
  const float* Wout  = (const float*)d_in[7];
  const float* bout  = (const float*)d_in[8];
  float* out = (float*)d_out;

  char* ws = (char*)d_ws;
  size_t off = 0;
  auto alloc = [&](size_t bytes) {
    char* p = ws + off;
    off = (off + bytes + 255) & ~(size_t)255;
    return p;
  };
  unsigned short* Sbuf    = (unsigned short*)alloc(48ull * 1024 * 1024 * 2);
  unsigned short* x_bf    = (unsigned short*)alloc(4096ull * 768 * 2);
  unsigned short* wqkv_bf = (unsigned short*)alloc(2304ull * 768 * 2);
  unsigned short* wout_bf = (unsigned short*)alloc(768ull * 768 * 2);
  unsigned short* q_bf    = (unsigned short*)alloc(48ull * 1024 * 64 * 2);
  unsigned short* k_bf    = (unsigned short*)alloc(48ull * 1024 * 64 * 2);
  unsigned short* vT_bf   = (unsigned short*)alloc(48ull * 64 * 1024 * 2);
  unsigned short* UT      = (unsigned short*)alloc(48ull * 64 * 1024 * 2);
  unsigned short* ctx     = (unsigned short*)alloc(4096ull * 768 * 2);
  if (off > ws_size) return;

  cvt3<<<dim3(5376), 256, 0, stream>>>(x, qkv_w, Wout, x_bf, wqkv_bf, wout_bf,
                                       786432, 442368, 147456);

  {  // GEMM1: qkv = x @ qkv_w^T, scatter q/k/vT  (128x128, BK=64, swizzle)
    GP p{};
    p.A = x_bf; p.B = wqkv_bf;
    p.K = 768; p.lda = 768; p.ldb = 768;
    p.q_out = q_bf; p.k_out = k_bf; p.vT_out = vT_bf;
    gemm_bt<2, 2, 4, 4, 1, 0, 1, 64><<<dim3(18, 32, 1), 256, 0, stream>>>(p);
  }
  {  // GEMM2: S[b,h] = q @ k^T (48 batches; f16 staged C store; K=64)
    GP p{};
    p.A = q_bf; p.B = k_bf;
    p.K = 64; p.lda = 64; p.ldb = 64;
    p.sA = 65536; p.sB = 65536;
    p.C = Sbuf; p.sC = 1048576; p.ldc = 1024;
    gemm_bt<2, 2, 4, 4, 0, 2, 0, 64><<<dim3(8, 8, 48), 256, 0, stream>>>(p);
  }
  mix_softmax<<<dim3(4096), 256, 0, stream>>>(Sbuf, W1, b1, W2, b2);
  {  // GEMM3: U^T[d][n] = vT @ A^T  (64x64 tiles, BK=128 -> 8 K-iters)
    GP p{};
    p.A = vT_bf; p.B = Sbuf;
    p.K = 1024; p.lda = 1024; p.ldb = 1024;
    p.sA = 65536; p.sB = 1048576;
    p.C = UT; p.sC = 65536; p.ldc = 1024;
    gemm_bt<1, 4, 4, 1, 0, 1, 0, 128><<<dim3(16, 1, 48), 256, 0, stream>>>(p);
  }
  {  // GEMM4: Y = A @ U; ctx = (1-2λ)U + 3λY  (64x64 tiles, BK=128)
    GP p{};
    p.A = Sbuf; p.B = UT;
    p.K = 1024; p.lda = 1024; p.ldb = 1024;
    p.sA = 1048576; p.sB = 65536;
    p.C = ctx; p.C2 = UT; p.lamb = lamb;
    gemm_bt<4, 1, 1, 4, 4, 0, 0, 128><<<dim3(1, 16, 48), 256, 0, stream>>>(p);
  }
  {  // GEMM5: out = ctx @ Wout^T + bout  (64x64 tiles, BK=128 -> 6 K-iters)
    GP p{};
    p.A = ctx; p.B = wout_bf;
    p.K = 768; p.lda = 768; p.ldb = 768;
    p.outF = out; p.bias = bout; p.ldc = 768;
    gemm_bt<2, 2, 2, 2, 2, 0, 1, 128><<<dim3(12, 64, 1), 256, 0, stream>>>(p);
  }
}

// Round 19
// 176.541 us; speedup vs baseline: 1.0120x; 1.0120x over previous
//
#include <hip/hip_runtime.h>
#include <hip/hip_bf16.h>

// Talking-heads attention + GFSA reaction, MI355X (gfx950).
//   attn_final = (1-2λ)A + 3λ A²  applied to v:
//   ctx = (1-2λ)(A@v) + 3λ A@(A@v)   -- never forms A@A.
// R18->R19: revert BK=128 (neutral/-1us) -> final best config = R12/R17:
// BK=64 everywhere, MFMA mix (wave-local, 1 barrier), f16 S, XOR-swizzled
// global_load_lds staging, fused epilogues, XCD swizzle on G1/G5.
// Measured 177.05-177.31 us, absmax 0.0625.

typedef __bf16 bf16x8 __attribute__((ext_vector_type(8)));
typedef float f32x4 __attribute__((ext_vector_type(4)));
typedef _Float16 half4v __attribute__((ext_vector_type(4)));
typedef _Float16 half2v __attribute__((ext_vector_type(2)));
typedef __fp16 fp16x2 __attribute__((ext_vector_type(2)));

#define DI __device__ __forceinline__

DI unsigned short f2bf(float f) {
  union { float f; unsigned u; } x; x.f = f;
  unsigned r = x.u + 0x7FFF + ((x.u >> 16) & 1);   // RNE
  return (unsigned short)(r >> 16);
}
DI float bf2f(unsigned short u) {
  union { unsigned u; float f; } x; x.u = ((unsigned)u) << 16; return x.f;
}
DI unsigned short f2h(float f) {
  union { _Float16 h; unsigned short u; } x;
  x.h = (_Float16)f;
  return x.u;
}
DI unsigned pk_bf16(float a, float b) {   // packs (a,b) -> 2xbf16, RNE
  unsigned r;
  asm("v_cvt_pk_bf16_f32 %0, %1, %2" : "=v"(r) : "v"(a), "v"(b));
  return r;
}
DI half2v pkrtz(float a, float b) {       // f32 pair -> packed f16 (RTZ)
  fp16x2 t = __builtin_amdgcn_cvt_pkrtz(a, b);
  union { fp16x2 a; half2v b; } u;
  u.a = t;
  return u.b;
}
DI void gload16(const unsigned short* g, unsigned short* l) {
  __builtin_amdgcn_global_load_lds(
      (const __attribute__((address_space(1))) unsigned int*)g,
      (__attribute__((address_space(3))) unsigned int*)l, 16, 0, 0);
}

DI f32x4 mfma1616(half4v a, half4v b, f32x4 c) {
  return __builtin_amdgcn_mfma_f32_16x16x16f16(a, b, c, 0, 0, 0);
}

struct GP {
  const unsigned short* A;
  const unsigned short* B;
  int K, lda, ldb, ldc;
  long sA, sB, sC;
  unsigned short* C;
  const unsigned short* C2;
  float* outF;
  const float* bias;
  const float* lamb;
  unsigned short* q_out;
  unsigned short* k_out;
  unsigned short* vT_out;
};

// C = A @ B^T, A:[M,K] bf16 row-major(lda), B:[N,K] bf16 row-major(ldb).
// Wave grid WMxWN, per-wave FMxFN frags of mfma_f32_16x16x32_bf16.
// BM=WM*FM*16, BN=WN*FN*16. BK=64. LDS XOR-swizzle via pre-swizzled global
// chunk index + linear global_load_lds (16B). STC: 1=bf16 staged C, 2=f16.
// SWZ: XCD-aware bijective block remap (requires gridDim.x*gridDim.y % 8 == 0).
template<int WM, int WN, int FM, int FN, int EPI, int STC, int SWZ>
__global__ __launch_bounds__(256) void gemm_bt(GP p) {
  constexpr int BM = WM * FM * 16, BN = WN * FN * 16;
  constexpr int LSZ = (BM * 64 + BN * 64) > (BM * BN) ? (BM * 64 + BN * 64)
                                                      : (BM * BN);
  __shared__ __align__(16) unsigned short ls[LSZ];
  unsigned short* lA = ls;
  unsigned short* lB = ls + BM * 64;
  const int tid = threadIdx.x, lane = tid & 63, wid = tid >> 6;
  const int wr = wid / WN, wc = wid % WN;
  int bx = blockIdx.x, by = blockIdx.y;
  if constexpr (SWZ) {
    int gx = gridDim.x;
    int nwg = gx * gridDim.y;
    int flat = by * gx + bx;
    int swz = (flat & 7) * (nwg >> 3) + (flat >> 3);
    bx = swz % gx;
    by = swz / gx;
  }
  const int m0 = by * BM, n0 = bx * BN;
  const int bz = blockIdx.z;
  const unsigned short* Ab = p.A + (long)bz * p.sA;
  const unsigned short* Bb = p.B + (long)bz * p.sB;

  f32x4 acc[FM][FN];
#pragma unroll
  for (int i = 0; i < FM; ++i)
#pragma unroll
    for (int j = 0; j < FN; ++j) acc[i][j] = (f32x4)0.f;

  for (int k0 = 0; k0 < p.K; k0 += 64) {
    __syncthreads();
#pragma unroll
    for (int i = 0; i < BM / 32; ++i) {
      int c = tid + i * 256, r = c >> 3, kc = c & 7, kg = kc ^ (r & 7);
      gload16(Ab + (long)(m0 + r) * p.lda + k0 + kg * 8, &lA[c * 8]);
    }
#pragma unroll
    for (int i = 0; i < BN / 32; ++i) {
      int c = tid + i * 256, r = c >> 3, kc = c & 7, kg = kc ^ (r & 7);
      gload16(Bb + (long)(n0 + r) * p.ldb + k0 + kg * 8, &lB[c * 8]);
    }
    __syncthreads();
#pragma unroll
    for (int half = 0; half < 2; ++half) {
      bf16x8 af[FM], bfr[FN];
#pragma unroll
      for (int mi = 0; mi < FM; ++mi) {
        int r = wr * FM * 16 + mi * 16 + (lane & 15);
        int kc = half * 4 + (lane >> 4);
        af[mi] = *(const bf16x8*)&lA[r * 64 + ((kc ^ (r & 7)) << 3)];
      }
#pragma unroll
      for (int ni = 0; ni < FN; ++ni) {
        int r = wc * FN * 16 + ni * 16 + (lane & 15);
        int kc = half * 4 + (lane >> 4);
        bfr[ni] = *(const bf16x8*)&lB[r * 64 + ((kc ^ (r & 7)) << 3)];
      }
#pragma unroll
      for (int mi = 0; mi < FM; ++mi)
#pragma unroll
        for (int ni = 0; ni < FN; ++ni)
          acc[mi][ni] = __builtin_amdgcn_mfma_f32_16x16x32_bf16(
              af[mi], bfr[ni], acc[mi][ni], 0, 0, 0);
    }
  }

  if constexpr (STC >= 1) {
    // Stage C-tile in LDS (chunk-XOR swizzle), then coalesced 16B writes.
    __syncthreads();
#pragma unroll
    for (int mi = 0; mi < FM; ++mi)
#pragma unroll
      for (int ni = 0; ni < FN; ++ni) {
        int row = wr * FM * 16 + mi * 16 + (lane >> 4) * 4;
        int col = wc * FN * 16 + ni * 16 + (lane & 15);
#pragma unroll
        for (int r2 = 0; r2 < 4; ++r2) {
          float v = acc[mi][ni][r2];
          ls[(row + r2) * BN + (col ^ ((row + r2) & 7) * 8)] =
              (STC == 2) ? f2h(v) : f2bf(v);
        }
      }
    __syncthreads();
    constexpr int CPR = BN / 8;           // 16B chunks per row
#pragma unroll
    for (int idx = tid; idx < BM * CPR; idx += 256) {
      int row = idx / CPR, cc = idx % CPR;
      uint4 d = *(const uint4*)&ls[row * BN + (cc ^ (row & 7)) * 8];
      *(uint4*)&p.C[(long)bz * p.sC + (long)(m0 + row) * p.ldc + n0 + cc * 8] = d;
    }
    return;
  }

#pragma unroll
  for (int mi = 0; mi < FM; ++mi)
#pragma unroll
    for (int ni = 0; ni < FN; ++ni) {
      const int rowb = m0 + wr * FM * 16 + mi * 16 + (lane >> 4) * 4;
      const int col = n0 + wc * FN * 16 + ni * 16 + (lane & 15);
      if constexpr (EPI == 1) {            // qkv scatter: q*SCALE, k, v^T
        int s = col / 768, rem = col - s * 768;
        int h = rem >> 6, d = rem & 63;
        int b = rowb >> 10, n = rowb & 1023;
        long ho = (long)(b * 12 + h);
        if (s == 2) {                      // 4 consecutive n -> one 8B store
          uint2 pk = { pk_bf16(acc[mi][ni][0], acc[mi][ni][1]),
                       pk_bf16(acc[mi][ni][2], acc[mi][ni][3]) };
          *(uint2*)&p.vT_out[(ho * 64 + d) * 1024 + n] = pk;
        } else {
#pragma unroll
          for (int r2 = 0; r2 < 4; ++r2) {
            float v = acc[mi][ni][r2];
            if (s == 0)
              p.q_out[(ho * 1024 + n + r2) * 64 + d] = f2bf(v * 0.125f);
            else
              p.k_out[(ho * 1024 + n + r2) * 64 + d] = f2bf(v);
          }
        }
      } else if constexpr (EPI == 2) {     // fp32 out + bias
        float bb = p.bias[col];
#pragma unroll
        for (int r2 = 0; r2 < 4; ++r2)
          p.outF[(long)(rowb + r2) * p.ldc + col] = acc[mi][ni][r2] + bb;
      } else if constexpr (EPI == 4) {     // ctx = (1-2λ)U + 3λ·Y
        int b = bz / 12, h = bz - b * 12;
        float lam = p.lamb[h];
        float a1 = 1.f - 2.f * lam, c3 = 3.f * lam;
        uint2 uq = *(const uint2*)&p.C2[(long)bz * 65536 + (long)col * 1024 + rowb];
        float uv[4] = { bf2f((unsigned short)(uq.x & 0xffff)),
                        bf2f((unsigned short)(uq.x >> 16)),
                        bf2f((unsigned short)(uq.y & 0xffff)),
                        bf2f((unsigned short)(uq.y >> 16)) };
#pragma unroll
        for (int r2 = 0; r2 < 4; ++r2) {
          float val = a1 * uv[r2] + c3 * acc[mi][ni][r2];
          p.C[((long)(b * 1024 + rowb + r2)) * 768 + h * 64 + col] = f2bf(val);
        }
      }
    }
}

// One block per (b,n) row. MFMA-based mix, WAVE-LOCAL phases (R12):
//   wave w owns columns [w*256, (w+1)*256): stages its slab (12 rows x 32
//   16B chunks via per-lane uint4 loads -> max MLP), premixes it
//   (L = W1f @ Sfrag + b1 via 16x16x16f16, k>=12 rows clamped under zero
//   weights), exp in regs, postmixes (swapped: out^T = P^T @ W2^T) into its
//   slab, stores its slab. Intra-wave LDS ordering replaces barriers; ONLY
//   the softmax-sum exchange barrier remains.
__global__ __launch_bounds__(256) void mix_softmax(
    unsigned short* S, const float* W1, const float* b1,
    const float* W2, const float* b2) {
  constexpr int RS = 1032;
  __shared__ __align__(16) unsigned short sld[12 * RS];
  __shared__ float red[4][16];
  const int tid = threadIdx.x, lane = tid & 63, wid = tid >> 6;
  const int bn = blockIdx.x, b = bn >> 10, n = bn & 1023;
  unsigned short* Sb = S + ((long)(b * 12) * 1024 + n) * 1024;

  // wave-local staging: 12 rows x 32 chunks of this wave's 256-col slab
#pragma unroll
  for (int i = 0; i < 6; ++i) {
    int flat = i * 64 + lane;                 // 0..383
    int row = flat >> 5, ch = (flat & 31) + wid * 32;
    uint4 d = *(const uint4*)(Sb + (long)row * 1048576 + ch * 8);
    *(uint4*)&sld[row * RS + ch * 8] = d;
  }
  // W fragments (A operand: row=lane&15 -> g, k=(lane>>4)*4+j -> h) + biases
  const int gr = lane & 15, kb = (lane >> 4) * 4;
  half4v w1f, w2f;
  f32x4 bias1;
  int ro[4];
#pragma unroll
  for (int j = 0; j < 4; ++j) {
    int k = kb + j;
    bool vw = (gr < 12) && (k < 12);
    w1f[j] = vw ? (_Float16)W1[gr * 12 + k] : (_Float16)0.f;
    w2f[j] = vw ? (_Float16)W2[gr * 12 + k] : (_Float16)0.f;
    bias1[j] = (k < 12) ? b1[k] : 0.f;       // premix D row = kb + r
    ro[j] = (k < 12 ? k : 11) * RS;          // clamped B-frag row offset
  }
  const float b2v = (gr < 12) ? b2[gr] : 0.f;  // postmix D col = gr
  f32x4 bias2v = { b2v, b2v, b2v, b2v };

  // premix on own slab (no barrier: intra-wave LDS ordering suffices)
  const _Float16* sh = (const _Float16*)sld;
  const int colb = wid * 256 + (lane & 15);
  f32x4 pv[16];
  float ssum[4] = { 0.f, 0.f, 0.f, 0.f };
#pragma unroll
  for (int c = 0; c < 16; ++c) {
    int col = colb + c * 16;
    half4v bf;
#pragma unroll
    for (int j = 0; j < 4; ++j) bf[j] = sh[ro[j] + col];
    f32x4 acc = mfma1616(w1f, bf, bias1);
#pragma unroll
    for (int r = 0; r < 4; ++r) {
      float e = __expf(acc[r]);
      pv[c][r] = e;
      ssum[r] += e;
    }
  }
#pragma unroll
  for (int r = 0; r < 4; ++r) {
#pragma unroll
    for (int m = 1; m < 16; m <<= 1) ssum[r] += __shfl_xor(ssum[r], m);
  }
  if ((lane & 15) == 0) {
#pragma unroll
    for (int r = 0; r < 4; ++r) red[wid][kb + r] = ssum[r];
  }
  __syncthreads();                           // the ONE cross-wave exchange
  float rinv[4];
#pragma unroll
  for (int r = 0; r < 4; ++r)
    rinv[r] = 1.f / (red[0][kb + r] + red[1][kb + r] +
                     red[2][kb + r] + red[3][kb + r]);
  // postmix into own slab, swapped: D[m-local][g]
#pragma unroll
  for (int c = 0; c < 16; ++c) {
    union { half4v h4; half2v h2[2]; } pf;
    pf.h2[0] = pkrtz(pv[c][0] * rinv[0], pv[c][1] * rinv[1]);
    pf.h2[1] = pkrtz(pv[c][2] * rinv[2], pv[c][3] * rinv[3]);
    f32x4 o = mfma1616(pf.h4, w2f, bias2v);
    if (gr < 12) {
      uint2 ov = { pk_bf16(o[0], o[1]), pk_bf16(o[2], o[3]) };
      *(uint2*)&sld[gr * RS + wid * 256 + c * 16 + kb] = ov;
    }
  }
  // store own slab (no barrier: all slab writes were by this wave)
#pragma unroll
  for (int i = 0; i < 6; ++i) {
    int flat = i * 64 + lane;
    int row = flat >> 5, ch = (flat & 31) + wid * 32;
    *(uint4*)(Sb + (long)row * 1048576 + ch * 8) =
        *(const uint4*)&sld[row * RS + ch * 8];
  }
}

// One kernel converting three fp32->bf16 regions (fewer graph nodes).
__global__ __launch_bounds__(256) void cvt3(
    const float* a, const float* b, const float* c,
    unsigned short* oa, unsigned short* ob, unsigned short* oc,
    int na, int nb, int nc) {
  int i = blockIdx.x * 256 + threadIdx.x;
  const float* src;
  unsigned short* dst;
  int j = i;
  if (i < na) { src = a; dst = oa; }
  else if (i < na + nb) { src = b; dst = ob; j = i - na; }
  else if (i < na + nb + nc) { src = c; dst = oc; j = i - na - nb; }
  else return;
  float4 v = *(const float4*)(src + (long)j * 4);
  uint2 o = { pk_bf16(v.x, v.y), pk_bf16(v.z, v.w) };
  *(uint2*)(dst + (long)j * 4) = o;
}

extern "C" void kernel_launch(void* const* d_in, const int* in_sizes, int n_in,
                              void* d_out, int out_size, void* d_ws,
                              size_t ws_size, hipStream_t stream) {
  const float* x     = (const float*)d_in[0];
  const float* qkv_w = (const float*)d_in[1];
  const float* W1    = (const float*)d_in[2];
  const float* b1    = (const float*)d_in[3];
  const float* W2    = (const float*)d_in[4];
  const float* b2    = (const float*)d_in[5];
  const float* lamb  = (const float*)d_in[6];
  const float* Wout  = (const float*)d_in[7];
  const float* bout  = (const float*)d_in[8];
  float* out = (float*)d_out;

  char* ws = (char*)d_ws;
  size_t off = 0;
  auto alloc = [&](size_t bytes) {
    char* p = ws + off;
    off = (off + bytes + 255) & ~(size_t)255;
    return p;
  };
  unsigned short* Sbuf    = (unsigned short*)alloc(48ull * 1024 * 1024 * 2);
  unsigned short* x_bf    = (unsigned short*)alloc(4096ull * 768 * 2);
  unsigned short* wqkv_bf = (unsigned short*)alloc(2304ull * 768 * 2);
  unsigned short* wout_bf = (unsigned short*)alloc(768ull * 768 * 2);
  unsigned short* q_bf    = (unsigned short*)alloc(48ull * 1024 * 64 * 2);
  unsigned short* k_bf    = (unsigned short*)alloc(48ull * 1024 * 64 * 2);
  unsigned short* vT_bf   = (unsigned short*)alloc(48ull * 64 * 1024 * 2);
  unsigned short* UT      = (unsigned short*)alloc(48ull * 64 * 1024 * 2);
  unsigned short* ctx     = (unsigned short*)alloc(4096ull * 768 * 2);
  if (off > ws_size) return;

  cvt3<<<dim3(5376), 256, 0, stream>>>(x, qkv_w, Wout, x_bf, wqkv_bf, wout_bf,
                                       786432, 442368, 147456);

  {  // GEMM1: qkv = x @ qkv_w^T, scatter q/k/vT  (128x128 tiles, XCD swizzle)
    GP p{};
    p.A = x_bf; p.B = wqkv_bf;
    p.K = 768; p.lda = 768; p.ldb = 768;
    p.q_out = q_bf; p.k_out = k_bf; p.vT_out = vT_bf;
    gemm_bt<2, 2, 4, 4, 1, 0, 1><<<dim3(18, 32, 1), 256, 0, stream>>>(p);
  }
  {  // GEMM2: S[b,h] = q @ k^T (48 batches; f16 staged C store)
    GP p{};
    p.A = q_bf; p.B = k_bf;
    p.K = 64; p.lda = 64; p.ldb = 64;
    p.sA = 65536; p.sB = 65536;
    p.C = Sbuf; p.sC = 1048576; p.ldc = 1024;
    gemm_bt<2, 2, 4, 4, 0, 2, 0><<<dim3(8, 8, 48), 256, 0, stream>>>(p);
  }
  mix_softmax<<<dim3(4096), 256, 0, stream>>>(Sbuf, W1, b1, W2, b2);
  {  // GEMM3: U^T[d][n] = vT @ A^T  (64x64 tiles -> 768 blocks)
    GP p{};
    p.A = vT_bf; p.B = Sbuf;
    p.K = 1024; p.lda = 1024; p.ldb = 1024;
    p.sA = 65536; p.sB = 1048576;
    p.C = UT; p.sC = 65536; p.ldc = 1024;
    gemm_bt<1, 4, 4, 1, 0, 1, 0><<<dim3(16, 1, 48), 256, 0, stream>>>(p);
  }
  {  // GEMM4: Y = A @ U; ctx = (1-2λ)U + 3λY  (64x64 tiles -> 768 blocks)
    GP p{};
    p.A = Sbuf; p.B = UT;
    p.K = 1024; p.lda = 1024; p.ldb = 1024;
    p.sA = 1048576; p.sB = 65536;
    p.C = ctx; p.C2 = UT; p.lamb = lamb;
    gemm_bt<4, 1, 1, 4, 4, 0, 0><<<dim3(1, 16, 48), 256, 0, stream>>>(p);
  }
  {  // GEMM5: out = ctx @ Wout^T + bout  (64x64 -> 768 blocks, XCD swizzle)
    GP p{};
    p.A = ctx; p.B = wout_bf;
    p.K = 768; p.lda = 768; p.ldb = 768;
    p.outF = out; p.bias = bout; p.ldc = 768;
    gemm_bt<2, 2, 2, 2, 2, 0, 1><<<dim3(12, 64, 1), 256, 0, stream>>>(p);
  }
}